// Round 1
// baseline (586.862 us; speedup 1.0000x reference)
//
#include <hip/hip_runtime.h>

#define N_ENT 400000
#define N_REL 500
#define N_TS 365
#define RANK 64
#define BATCH 256

// ---------------------------------------------------------------------------
// Kernel 1: per-batch prep. Computes V[i][k] = 2*(lhs*rel_ - te*tr) and
// row_bias[i] = sum_k 2*te*(lhs*tr + te*rel_).  256 blocks x 64 threads.
// ---------------------------------------------------------------------------
__global__ void prep_kernel(const float* __restrict__ E0,
                            const float* __restrict__ E1,
                            const float* __restrict__ E2,
                            const float* __restrict__ E3,
                            const float* __restrict__ E4,
                            const int* __restrict__ x,
                            float* __restrict__ V,     // [BATCH][RANK]
                            float* __restrict__ bias)  // [BATCH]
{
    const int i = blockIdx.x;   // batch row
    const int k = threadIdx.x;  // rank index (one wave of 64)

    const int i0 = x[i * 4 + 0];
    const int i1 = x[i * 4 + 1];
    const int i3 = x[i * 4 + 3];

    const float lhs = E0[i0 * RANK + k];
    const float rel = E1[i1 * RANK + k];
    const float te  = E2[i3 * RANK + k];
    const float tr  = E3[i3 * RANK + k];

    // complex_mul(rel, comp_time) with half-width 32
    const int  kh = k & 31;
    const float a = E1[i1 * RANK + kh];
    const float b = E1[i1 * RANK + 32 + kh];
    const float c = E4[i3 * RANK + kh];
    const float d = E4[i3 * RANK + 32 + kh];
    const float cm = (k < 32) ? (a * c + b * d) : (a * d - b * c);
    const float rel_ = rel + cm;

    V[i * RANK + k] = 2.0f * (lhs * rel_ - te * tr);

    float rb = 2.0f * te * (lhs * tr + te * rel_);
    #pragma unroll
    for (int off = 32; off > 0; off >>= 1)
        rb += __shfl_down(rb, off, 64);
    if (k == 0) bias[i] = rb;
}

// ---------------------------------------------------------------------------
// Kernel 2: tail outputs — cl_loss scalar + copies of E2/E3/E4 rows [0,364).
// ---------------------------------------------------------------------------
__global__ void tail_kernel(const float* __restrict__ E2,
                            const float* __restrict__ E3,
                            const float* __restrict__ E4,
                            float* __restrict__ out)
{
    const long long SCORES = (long long)BATCH * N_ENT;  // 102,400,000
    const int CP = (N_TS - 1) * RANK;                   // 23,296
    const int idx = blockIdx.x * blockDim.x + threadIdx.x;
    if (idx == 0) out[SCORES] = 0.0f;  // cl_loss
    if (idx < CP) {
        out[SCORES + 1 + 0LL * CP + idx] = E2[idx];
        out[SCORES + 1 + 1LL * CP + idx] = E3[idx];
        out[SCORES + 1 + 2LL * CP + idx] = E4[idx];
    }
}

// ---------------------------------------------------------------------------
// Kernel 3: scores[i][j] = V[i] . E0[j] + bias[i].
// Thread j owns one entity column: E0 row in 64 VGPRs (float4 loads),
// V read at thread-uniform addresses (scalarizes to s_load), coalesced
// dword stores across lanes for each batch row i.
// ---------------------------------------------------------------------------
__global__ __launch_bounds__(256) void scores_kernel(
    const float* __restrict__ E0,
    const float* __restrict__ V,
    const float* __restrict__ bias,
    float* __restrict__ out)
{
    const int j = blockIdx.x * 256 + threadIdx.x;
    if (j >= N_ENT) return;

    float r[RANK];
    const float4* rowp = reinterpret_cast<const float4*>(E0 + (size_t)j * RANK);
    #pragma unroll
    for (int k4 = 0; k4 < RANK / 4; ++k4) {
        const float4 t = rowp[k4];
        r[k4 * 4 + 0] = t.x;
        r[k4 * 4 + 1] = t.y;
        r[k4 * 4 + 2] = t.z;
        r[k4 * 4 + 3] = t.w;
    }

    #pragma unroll 1
    for (int i = 0; i < BATCH; ++i) {
        float acc = bias[i];
        #pragma unroll
        for (int k = 0; k < RANK; ++k)
            acc = fmaf(V[i * RANK + k], r[k], acc);
        out[(size_t)i * N_ENT + j] = acc;
    }
}

// ---------------------------------------------------------------------------
extern "C" void kernel_launch(void* const* d_in, const int* in_sizes, int n_in,
                              void* d_out, int out_size, void* d_ws, size_t ws_size,
                              hipStream_t stream) {
    const float* E0 = (const float*)d_in[0];
    const float* E1 = (const float*)d_in[1];
    const float* E2 = (const float*)d_in[2];
    const float* E3 = (const float*)d_in[3];
    const float* E4 = (const float*)d_in[4];
    const int*   x  = (const int*)d_in[5];

    float* out = (float*)d_out;

    float* V    = (float*)d_ws;                       // 256*64 floats = 64 KiB
    float* bias = (float*)d_ws + BATCH * RANK;        // 256 floats

    prep_kernel<<<BATCH, RANK, 0, stream>>>(E0, E1, E2, E3, E4, x, V, bias);

    const int CP = (N_TS - 1) * RANK;
    tail_kernel<<<(CP + 255) / 256, 256, 0, stream>>>(E2, E3, E4, out);

    const int nblk = (N_ENT + 255) / 256;  // 1563
    scores_kernel<<<nblk, 256, 0, stream>>>(E0, V, bias, out);
}

// Round 2
// 132.007 us; speedup vs baseline: 4.4457x; 4.4457x over previous
//
#include <hip/hip_runtime.h>

#define N_ENT 400000
#define N_REL 500
#define N_TS 365
#define RANK 64
#define BATCH 256

typedef __attribute__((ext_vector_type(8))) __bf16 bf16x8;
typedef __attribute__((ext_vector_type(16))) float f32x16;

// ---------------------------------------------------------------------------
// Kernel 1: per-batch prep. Computes V[i][k] = 2*(lhs*rel_ - te*tr) (bf16) and
// row_bias[i] = sum_k 2*te*(lhs*tr + te*rel_).  256 blocks x 64 threads.
// ---------------------------------------------------------------------------
__global__ void prep_kernel(const float* __restrict__ E0,
                            const float* __restrict__ E1,
                            const float* __restrict__ E2,
                            const float* __restrict__ E3,
                            const float* __restrict__ E4,
                            const int* __restrict__ x,
                            __bf16* __restrict__ Vbf,  // [BATCH][RANK]
                            float* __restrict__ bias)  // [BATCH]
{
    const int i = blockIdx.x;   // batch row
    const int k = threadIdx.x;  // rank index (one wave of 64)

    const int i0 = x[i * 4 + 0];
    const int i1 = x[i * 4 + 1];
    const int i3 = x[i * 4 + 3];

    const float lhs = E0[i0 * RANK + k];
    const float rel = E1[i1 * RANK + k];
    const float te  = E2[i3 * RANK + k];
    const float tr  = E3[i3 * RANK + k];

    // complex_mul(rel, comp_time) with half-width 32
    const int  kh = k & 31;
    const float a = E1[i1 * RANK + kh];
    const float b = E1[i1 * RANK + 32 + kh];
    const float c = E4[i3 * RANK + kh];
    const float d = E4[i3 * RANK + 32 + kh];
    const float cm = (k < 32) ? (a * c + b * d) : (a * d - b * c);
    const float rel_ = rel + cm;

    const float v = 2.0f * (lhs * rel_ - te * tr);
    Vbf[i * RANK + k] = (__bf16)v;

    float rb = 2.0f * te * (lhs * tr + te * rel_);
    #pragma unroll
    for (int off = 32; off > 0; off >>= 1)
        rb += __shfl_down(rb, off, 64);
    if (k == 0) bias[i] = rb;
}

// ---------------------------------------------------------------------------
// Kernel 2: tail outputs — cl_loss scalar + copies of E2/E3/E4 rows [0,364).
// ---------------------------------------------------------------------------
__global__ void tail_kernel(const float* __restrict__ E2,
                            const float* __restrict__ E3,
                            const float* __restrict__ E4,
                            float* __restrict__ out)
{
    const long long SCORES = (long long)BATCH * N_ENT;  // 102,400,000
    const int CP = (N_TS - 1) * RANK;                   // 23,296
    const int idx = blockIdx.x * blockDim.x + threadIdx.x;
    if (idx == 0) out[SCORES] = 0.0f;  // cl_loss
    if (idx < CP) {
        out[SCORES + 1 + 0LL * CP + idx] = E2[idx];
        out[SCORES + 1 + 1LL * CP + idx] = E3[idx];
        out[SCORES + 1 + 2LL * CP + idx] = E4[idx];
    }
}

// ---------------------------------------------------------------------------
// Kernel 3: scores = V @ E0^T + bias via mfma_f32_32x32x16_bf16.
//   Block = 256 threads = 4 waves; block owns 128 entity columns, wave owns 32.
//   B-frags (E0 rows, fp32->bf16 in-register) held in VGPRs for the whole
//   M loop; A-frags read from the L2-resident 32 KB bf16 V.
//   A layout: lane holds A[row=l&31][k=(l>>5)*8+j] per K=16 instruction.
//   B layout: lane holds B[k=(l>>5)*8+j][col=l&31].
//   C layout (verified m74/m101): col=lane&31, row=(reg&3)+8*(reg>>2)+4*(lane>>5).
// ---------------------------------------------------------------------------
__global__ __launch_bounds__(256) void scores_mfma(
    const float* __restrict__ E0,
    const __bf16* __restrict__ Vbf,
    const float* __restrict__ bias,
    float* __restrict__ out)
{
    const int lane  = threadIdx.x & 63;
    const int wid   = threadIdx.x >> 6;                 // 0..3
    const int col   = blockIdx.x * 128 + wid * 32 + (lane & 31);  // entity
    const int khalf = (lane >> 5) * 8;                  // 0 or 8

    // ---- B fragments: 4 x (K=16) over K=64, converted fp32 -> bf16 ----
    bf16x8 bfrag[4];
    const float* erow = E0 + (size_t)col * RANK;
    #pragma unroll
    for (int f = 0; f < 4; ++f) {
        const int kb = f * 16 + khalf;
        const float4 u0 = *reinterpret_cast<const float4*>(erow + kb);
        const float4 u1 = *reinterpret_cast<const float4*>(erow + kb + 4);
        bfrag[f][0] = (__bf16)u0.x;  bfrag[f][1] = (__bf16)u0.y;
        bfrag[f][2] = (__bf16)u0.z;  bfrag[f][3] = (__bf16)u0.w;
        bfrag[f][4] = (__bf16)u1.x;  bfrag[f][5] = (__bf16)u1.y;
        bfrag[f][6] = (__bf16)u1.z;  bfrag[f][7] = (__bf16)u1.w;
    }

    // ---- loop over 8 M-tiles of 32 batch rows ----
    #pragma unroll 1
    for (int mt = 0; mt < 8; ++mt) {
        const __bf16* arow = Vbf + (size_t)(mt * 32 + (lane & 31)) * RANK + khalf;

        f32x16 acc;
        #pragma unroll
        for (int j = 0; j < 16; ++j) acc[j] = 0.0f;

        #pragma unroll
        for (int f = 0; f < 4; ++f) {
            const bf16x8 afrag = *reinterpret_cast<const bf16x8*>(arow + f * 16);
            acc = __builtin_amdgcn_mfma_f32_32x32x16_bf16(afrag, bfrag[f], acc, 0, 0, 0);
        }

        const int mbase = mt * 32 + 4 * (lane >> 5);
        #pragma unroll
        for (int j = 0; j < 16; ++j) {
            const int m = mbase + (j & 3) + 8 * (j >> 2);
            out[(size_t)m * N_ENT + col] = acc[j] + bias[m];
        }
    }
}

// ---------------------------------------------------------------------------
extern "C" void kernel_launch(void* const* d_in, const int* in_sizes, int n_in,
                              void* d_out, int out_size, void* d_ws, size_t ws_size,
                              hipStream_t stream) {
    const float* E0 = (const float*)d_in[0];
    const float* E1 = (const float*)d_in[1];
    const float* E2 = (const float*)d_in[2];
    const float* E3 = (const float*)d_in[3];
    const float* E4 = (const float*)d_in[4];
    const int*   x  = (const int*)d_in[5];

    float* out = (float*)d_out;

    float*  bias = (float*)d_ws;                    // 256 floats = 1 KiB
    __bf16* Vbf  = (__bf16*)((char*)d_ws + 1024);   // 256*64 bf16 = 32 KiB

    prep_kernel<<<BATCH, RANK, 0, stream>>>(E0, E1, E2, E3, E4, x, Vbf, bias);

    const int CP = (N_TS - 1) * RANK;
    tail_kernel<<<(CP + 255) / 256, 256, 0, stream>>>(E2, E3, E4, out);

    const int nblk = N_ENT / 128;  // 3125 (exact)
    scores_mfma<<<nblk, 256, 0, stream>>>(E0, Vbf, bias, out);
}